// Round 7
// baseline (3037.516 us; speedup 1.0000x reference)
//
#include <hip/hip_runtime.h>

#define F_IN 512
#define HID 128
#define KHOPS 10
#define COUT 10

typedef unsigned int uint;
typedef unsigned short ushort;
typedef float f32x4 __attribute__((ext_vector_type(4)));
typedef short bf16x8 __attribute__((ext_vector_type(8)));
typedef int v16i __attribute__((ext_vector_type(16)));

__device__ __forceinline__ uint f2bf1(float f) {
    uint u = __float_as_uint(f);
    return (u + 0x7fffu + ((u >> 16) & 1u)) >> 16;   // RNE
}
__device__ __forceinline__ uint packbf(float a, float b) {
    return f2bf1(a) | (f2bf1(b) << 16);
}
__device__ __forceinline__ float bflo(uint u) { return __uint_as_float(u << 16); }
__device__ __forceinline__ float bfhi(uint u) { return __uint_as_float(u & 0xffff0000u); }

// ---------------- W_in -> bf16, pre-swizzled into MFMA B-fragment lane order ----------------
__global__ __launch_bounds__(256) void wprep_kernel(
    const float* __restrict__ Win, ushort* __restrict__ Wsw)
{
    const int t = blockIdx.x * blockDim.x + threadIdx.x;
    if (t >= 2 * 16 * 8 * 64) return;
    const int l = t & 63;
    const int c = (t >> 6) & 7;
    const int s = (t >> 9) & 15;
    const int br = t >> 13;
    const int col = c * 16 + (l & 15);
    const int k0 = s * 32 + (l >> 4) * 8;
    const float* W = Win + (size_t)br * F_IN * HID;
    uint o0 = packbf(W[(size_t)(k0 + 0) * HID + col], W[(size_t)(k0 + 1) * HID + col]);
    uint o1 = packbf(W[(size_t)(k0 + 2) * HID + col], W[(size_t)(k0 + 3) * HID + col]);
    uint o2 = packbf(W[(size_t)(k0 + 4) * HID + col], W[(size_t)(k0 + 5) * HID + col]);
    uint o3 = packbf(W[(size_t)(k0 + 6) * HID + col], W[(size_t)(k0 + 7) * HID + col]);
    *(uint4*)(Wsw + (size_t)t * 8) = make_uint4(o0, o1, o2, o3);
}

// ---------------- GEMM via MFMA: h = bf16(x @ W + b) ----------------
__global__ __launch_bounds__(256) void gemm_mfma_kernel(
    const float* __restrict__ x, const ushort* __restrict__ Wsw,
    const float* __restrict__ bin, uint* __restrict__ h1, uint* __restrict__ h2, int n)
{
    const int br = blockIdx.y;
    const uint4* Wb = (const uint4*)(Wsw + (size_t)br * 16 * 8 * 64 * 8);
    const float* bias = bin + br * HID;
    uint* h = br ? h2 : h1;

    const int w = threadIdx.x >> 6;
    const int lane = threadIdx.x & 63;
    const int r16 = lane & 15;
    const int kg = lane >> 4;

    const int rowbase = blockIdx.x * 128 + w * 32;

    f32x4 acc[2][8];
#pragma unroll
    for (int f = 0; f < 2; ++f)
#pragma unroll
        for (int c = 0; c < 8; ++c) acc[f][c] = (f32x4)0.f;

    int rA0 = rowbase + r16;      if (rA0 > n - 1) rA0 = n - 1;
    int rA1 = rowbase + 16 + r16; if (rA1 > n - 1) rA1 = n - 1;
    const float* xp0 = x + (size_t)rA0 * F_IN + kg * 8;
    const float* xp1 = x + (size_t)rA1 * F_IN + kg * 8;

    for (int s = 0; s < 16; ++s) {
        const float4 a0lo = *(const float4*)(xp0 + s * 32);
        const float4 a0hi = *(const float4*)(xp0 + s * 32 + 4);
        const float4 a1lo = *(const float4*)(xp1 + s * 32);
        const float4 a1hi = *(const float4*)(xp1 + s * 32 + 4);
        union { uint4 u; bf16x8 v; } af0, af1;
        af0.u = make_uint4(packbf(a0lo.x, a0lo.y), packbf(a0lo.z, a0lo.w),
                           packbf(a0hi.x, a0hi.y), packbf(a0hi.z, a0hi.w));
        af1.u = make_uint4(packbf(a1lo.x, a1lo.y), packbf(a1lo.z, a1lo.w),
                           packbf(a1hi.x, a1hi.y), packbf(a1hi.z, a1hi.w));
        const uint4* wq = Wb + (size_t)(s * 8) * 64 + lane;
#pragma unroll
        for (int c = 0; c < 8; ++c) {
            union { uint4 u; bf16x8 v; } bfr;
            bfr.u = wq[c * 64];
            acc[0][c] = __builtin_amdgcn_mfma_f32_16x16x32_bf16(af0.v, bfr.v, acc[0][c], 0, 0, 0);
            acc[1][c] = __builtin_amdgcn_mfma_f32_16x16x32_bf16(af1.v, bfr.v, acc[1][c], 0, 0, 0);
        }
    }

    float bv[8];
#pragma unroll
    for (int c = 0; c < 8; ++c) bv[c] = bias[c * 16 + r16];

#pragma unroll
    for (int f = 0; f < 2; ++f)
#pragma unroll
        for (int c = 0; c < 8; ++c)
#pragma unroll
            for (int i = 0; i < 4; ++i) {
                const float v = acc[f][c][i] + bv[c];
                const float o = __shfl_xor(v, 1);
                const int row = rowbase + f * 16 + kg * 4 + i;
                if (!(lane & 1) && row < n)
                    h[(size_t)row * 64 + c * 8 + (r16 >> 1)] = packbf(v, o);
            }
}

// ---------------- CSR build ----------------
// Packed edge record (temp): lo = (col << 8) | rowlocal, hi = w bits.
// Final cw record: lo = col*256 (byte offset into a 256B h row), hi = w bits.

__global__ void bhist_kernel(const int* __restrict__ r1, int E1,
                             const int* __restrict__ r2, int E2,
                             int* __restrict__ bcnt, int nb)
{
    extern __shared__ int sh[];
    const int br = blockIdx.y;
    const int* rows = br ? r2 : r1;
    const int E = br ? E2 : E1;
    int* bc = bcnt + (size_t)br * nb;
    for (int i = threadIdx.x; i < nb; i += blockDim.x) sh[i] = 0;
    __syncthreads();
    for (int i = blockIdx.x * blockDim.x + threadIdx.x; i < E; i += gridDim.x * blockDim.x)
        atomicAdd(&sh[rows[i] >> 6], 1);
    __syncthreads();
    for (int i = threadIdx.x; i < nb; i += blockDim.x)
        if (sh[i]) atomicAdd(&bc[i], sh[i]);
}

__global__ __launch_bounds__(256) void bscan_kernel(
    const int* __restrict__ bcnt, int* __restrict__ bbase, int* __restrict__ bcur,
    int* __restrict__ rowp1, int* __restrict__ rowp2,
    int nb, int n, int E1, int E2)
{
    __shared__ int ssum[256];
    const int br = blockIdx.y;
    const int* bc = bcnt + (size_t)br * nb;
    int* bb = bbase + (size_t)br * (nb + 1);
    int* cur = bcur + (size_t)br * nb;
    int* rowp = br ? rowp2 : rowp1;
    const int E = br ? E2 : E1;
    const int t = threadIdx.x;
    const int chunk = (nb + 255) / 256;
    const int start = t * chunk;
    const int end = (start + chunk < nb) ? start + chunk : nb;
    int sum = 0;
    for (int i = start; i < end; ++i) sum += bc[i];
    ssum[t] = sum;
    __syncthreads();
    if (t == 0) {
        int run = 0;
        for (int i = 0; i < 256; ++i) { int v = ssum[i]; ssum[i] = run; run += v; }
        bb[nb] = E;
        rowp[n] = E;
    }
    __syncthreads();
    int run = ssum[t];
    for (int i = start; i < end; ++i) {
        bb[i] = run; cur[i] = run; run += bc[i];
    }
}

#define SCAT_BLOCKS 256
__global__ __launch_bounds__(256) void bscat_kernel(
    const int* __restrict__ r1, const int* __restrict__ c1, const float* __restrict__ w1, int E1,
    const int* __restrict__ r2, const int* __restrict__ c2, const float* __restrict__ w2, int E2,
    int* __restrict__ bcur, int2* __restrict__ t1, int2* __restrict__ t2, int nb)
{
    extern __shared__ int sh[];
    int* lh = sh;
    int* lbase = sh + nb;
    const int br = blockIdx.y;
    const int* rows = br ? r2 : r1;
    const int* cols = br ? c2 : c1;
    const float* w  = br ? w2 : w1;
    const int E = br ? E2 : E1;
    int* cur = bcur + (size_t)br * nb;
    int2* tcw = br ? t2 : t1;
    const int t = threadIdx.x;

    for (int i = t; i < nb; i += 256) lh[i] = 0;
    __syncthreads();

    const int per = (E + SCAT_BLOCKS - 1) / SCAT_BLOCKS;
    const int c0 = blockIdx.x * per;
    const int cend = (c0 + per < E) ? c0 + per : E;

    for (int i = c0 + t; i < cend; i += 256)
        atomicAdd(&lh[rows[i] >> 6], 1);
    __syncthreads();
    for (int b = t; b < nb; b += 256) {
        int c = lh[b];
        lbase[b] = c ? atomicAdd(&cur[b], c) : 0;
        lh[b] = 0;
    }
    __syncthreads();
    for (int i = c0 + t; i < cend; i += 256) {
        int r = rows[i];
        int b = r >> 6;
        int p = atomicAdd(&lh[b], 1);
        uint lo = ((uint)cols[i] << 8) | (uint)(r & 63);
        tcw[lbase[b] + p] = make_int2((int)lo, __float_as_int(w[i]));
    }
}

__global__ __launch_bounds__(256) void bsort_kernel(
    const int* __restrict__ bbase,
    const int2* __restrict__ t1, const int2* __restrict__ t2,
    int* __restrict__ rowp1, int* __restrict__ rowp2,
    int2* __restrict__ cw1, int2* __restrict__ cw2, int nb, int n)
{
    __shared__ int cnt[64], soff[64], pos[64];
    const int br = blockIdx.y;
    const int* bb = bbase + (size_t)br * (nb + 1);
    const int2* tcw = br ? t2 : t1;
    int* rowp = br ? rowp2 : rowp1;
    int2* cw = br ? cw2 : cw1;
    const int b = blockIdx.x;
    const int t = threadIdx.x;
    const int base = bb[b];
    const int m = bb[b + 1] - base;
    if (t < 64) cnt[t] = 0;
    __syncthreads();
    for (int i = t; i < m; i += 256) atomicAdd(&cnt[(uint)tcw[base + i].x & 63], 1);
    __syncthreads();
    if (t == 0) {
        int run = 0;
#pragma unroll
        for (int r = 0; r < 64; ++r) { soff[r] = run; run += cnt[r]; }
    }
    __syncthreads();
    if (t < 64) {
        pos[t] = soff[t];
        int g = b * 64 + t;
        if (g < n) rowp[g] = base + soff[t];
    }
    __syncthreads();
    for (int i = t; i < m; i += 256) {
        int2 e = tcw[base + i];
        int r = (uint)e.x & 63;
        int p = atomicAdd(&pos[r], 1);
        cw[base + p] = make_int2((int)((uint)e.x & 0xFFFFFF00u), e.y);  // col*256 byte offset
    }
}

// ---------------- SpMM (s_load metadata, saddr bf16 gather) + fused z2 ----------------
struct BrArgs {
    const int* rowp;
    const int2* cw;
    const uint* hin;
    uint* hout;
    const float* Wo;
};

__global__ __launch_bounds__(256) void spmm2_kernel(
    BrArgs A, BrArgs B, const float* __restrict__ fW, int k,
    float* __restrict__ z2, int storeH, int n)
{
    const int bid = blockIdx.x;
    const int br = bid & 1;
    const int wid = (bid >> 1) * 4 + (threadIdx.x >> 6);
    if (wid >= n) return;
    const int*   rowp = br ? B.rowp : A.rowp;
    const int2*  cw   = br ? B.cw   : A.cw;
    const uint*  hin  = br ? B.hin  : A.hin;
    uint*        hout = br ? B.hout : A.hout;
    const float* Wo   = br ? B.Wo   : A.Wo;
    const int lane = threadIdx.x & 63;
    const uint laneB = (uint)lane * 4u;               // per-lane byte offset within a 256B row
    const char* hbase = (const char*)hin;

    float w0[COUT], w1[COUT];
    const float* wp = Wo + (size_t)(lane * 2) * COUT;
#pragma unroll
    for (int c = 0; c < COUT; ++c) { w0[c] = wp[c]; w1[c] = wp[COUT + c]; }

    int s = rowp[wid];
    int e = rowp[wid + 1];
    s = __builtin_amdgcn_readfirstlane(s);
    e = __builtin_amdgcn_readfirstlane(e);

    float2 acc = make_float2(0.f, 0.f);
    int i = s;

    // full 16-edge chunks: 2x s_load_dwordx16 -> 32 SGPRs of metadata
    while (e - i >= 16) {
        v16i e0v, e1v;
        asm volatile("s_load_dwordx16 %0, %2, 0x0\n\t"
                     "s_load_dwordx16 %1, %2, 0x40\n\t"
                     "s_waitcnt lgkmcnt(0)"
                     : "=s"(e0v), "=s"(e1v) : "s"(cw + i));
#pragma unroll
        for (int j = 0; j < 8; ++j) {
            const uint boff = (uint)e0v[2 * j];
            const float q = __int_as_float(e0v[2 * j + 1]);
            const uint g = *(const uint*)(hbase + (size_t)boff + laneB);
            acc.x = fmaf(q, bflo(g), acc.x);
            acc.y = fmaf(q, bfhi(g), acc.y);
        }
#pragma unroll
        for (int j = 0; j < 8; ++j) {
            const uint boff = (uint)e1v[2 * j];
            const float q = __int_as_float(e1v[2 * j + 1]);
            const uint g = *(const uint*)(hbase + (size_t)boff + laneB);
            acc.x = fmaf(q, bflo(g), acc.x);
            acc.y = fmaf(q, bfhi(g), acc.y);
        }
        i += 16;
    }
    // masked final chunk (cw arrays have 128B slack; invalid edges get boff=0, q=0)
    const int rem = e - i;
    if (rem > 0) {
        v16i e0v, e1v;
        asm volatile("s_load_dwordx16 %0, %2, 0x0\n\t"
                     "s_load_dwordx16 %1, %2, 0x40\n\t"
                     "s_waitcnt lgkmcnt(0)"
                     : "=s"(e0v), "=s"(e1v) : "s"(cw + i));
#pragma unroll
        for (int j = 0; j < 16; ++j) {
            uint boff = (uint)((j < 8) ? e0v[2 * j] : e1v[2 * (j - 8)]);
            float q = __int_as_float((j < 8) ? e0v[2 * j + 1] : e1v[2 * (j - 8) + 1]);
            if (j >= rem) { boff = 0u; q = 0.f; }   // uniform -> s_cselect
            const uint g = *(const uint*)(hbase + (size_t)boff + laneB);
            acc.x = fmaf(q, bflo(g), acc.x);
            acc.y = fmaf(q, bfhi(g), acc.y);
        }
    }

    if (storeH)
        hout[(size_t)wid * 64 + lane] = packbf(acc.x, acc.y);

    const float fw = fW[br * (KHOPS + 1) + k + 1];
    float zadd = 0.f;
#pragma unroll
    for (int c = 0; c < COUT; ++c) {
        float pp = fmaf(acc.x, w0[c], acc.y * w1[c]);
#pragma unroll
        for (int off = 32; off; off >>= 1) pp += __shfl_xor(pp, off);
        if (lane == c) zadd = pp;
    }
    if (lane < COUT) {
        const size_t o = (size_t)wid * (2 * COUT) + br * COUT + lane;
        z2[o] += fw * zadd;
    }
}

// ---------------- z2 init: fw0 * (h0 @ Wout) per branch ----------------
__global__ __launch_bounds__(256) void zacc2_kernel(
    const uint* __restrict__ h1, const uint* __restrict__ h2,
    const float* __restrict__ Wout, const float* __restrict__ fW,
    float* __restrict__ z2, int n)
{
    const int wid = (blockIdx.x * blockDim.x + threadIdx.x) >> 6;
    if (wid >= n) return;
    const int lane = threadIdx.x & 63;
    const uint u1 = h1[(size_t)wid * 64 + lane];
    const uint u2 = h2[(size_t)wid * 64 + lane];
    const float a1 = bflo(u1), b1v = bfhi(u1);
    const float a2 = bflo(u2), b2v = bfhi(u2);
    const float* wp1 = Wout + (size_t)(lane * 2) * COUT;
    const float* wp2 = Wout + (size_t)HID * COUT + (size_t)(lane * 2) * COUT;
    float zv1 = 0.f, zv2 = 0.f;
#pragma unroll
    for (int c = 0; c < COUT; ++c) {
        float p1 = fmaf(a1, wp1[c], b1v * wp1[COUT + c]);
        float p2 = fmaf(a2, wp2[c], b2v * wp2[COUT + c]);
#pragma unroll
        for (int off = 32; off; off >>= 1) { p1 += __shfl_xor(p1, off); p2 += __shfl_xor(p2, off); }
        if (lane == c) { zv1 = p1; zv2 = p2; }
    }
    if (lane < COUT) {
        z2[(size_t)wid * (2 * COUT) + lane]        = fW[0] * zv1;
        z2[(size_t)wid * (2 * COUT) + COUT + lane] = fW[KHOPS + 1] * zv2;
    }
}

// ---------------- log_softmax(z2_br0 + z2_br1 + bias) ----------------
__global__ void logsm_kernel(const float* __restrict__ z2, const float* __restrict__ bout,
                             float* __restrict__ out, int n)
{
    const int r = blockIdx.x * blockDim.x + threadIdx.x;
    if (r >= n) return;
    float v[COUT];
    float m = -1e30f;
#pragma unroll
    for (int c = 0; c < COUT; ++c) {
        v[c] = z2[(size_t)r * (2 * COUT) + c] + z2[(size_t)r * (2 * COUT) + COUT + c] + bout[c];
        m = fmaxf(m, v[c]);
    }
    float s = 0.f;
#pragma unroll
    for (int c = 0; c < COUT; ++c) s += expf(v[c] - m);
    const float l = logf(s) + m;
#pragma unroll
    for (int c = 0; c < COUT; ++c) out[(size_t)r * COUT + c] = v[c] - l;
}

extern "C" void kernel_launch(void* const* d_in, const int* in_sizes, int n_in,
                              void* d_out, int out_size, void* d_ws, size_t ws_size,
                              hipStream_t stream)
{
    const float* x    = (const float*)d_in[0];
    const int*   ei1  = (const int*)d_in[1];
    const float* ew1  = (const float*)d_in[2];
    const int*   ei2  = (const int*)d_in[3];
    const float* ew2  = (const float*)d_in[4];
    const float* Win  = (const float*)d_in[5];
    const float* bin  = (const float*)d_in[6];
    const float* fW   = (const float*)d_in[7];
    const float* Wout = (const float*)d_in[8];
    const float* bout = (const float*)d_in[9];
    const int n  = in_sizes[0] / F_IN;
    const int E1 = in_sizes[2];
    const int E2 = in_sizes[4];
    const int Emax = E1 > E2 ? E1 : E2;
    const int nb = (n + 63) / 64;
    float* zout = (float*)d_out;

    char* p = (char*)d_ws;
    auto alloc = [&](size_t bytes) { char* r = p; p += (bytes + 255) & ~(size_t)255; return r; };
    char* regA = alloc((size_t)4 * n * 64 * 4);
    uint* h1A = (uint*)regA;
    uint* h1B = (uint*)(regA + (size_t)n * 64 * 4);
    uint* h2A = (uint*)(regA + (size_t)2 * n * 64 * 4);
    uint* h2B = (uint*)(regA + (size_t)3 * n * 64 * 4);
    int2* tcw1 = (int2*)regA;
    int2* tcw2 = (int2*)(regA + (size_t)Emax * 8);
    int2* cw1  = (int2*)alloc((size_t)Emax * 8 + 128);   // +128B slack for masked chunk over-read
    int2* cw2  = (int2*)alloc((size_t)Emax * 8 + 128);
    int*  rowp1 = (int*)alloc((size_t)(n + 1) * 4);
    int*  rowp2 = (int*)alloc((size_t)(n + 1) * 4);
    float* z2  = (float*)alloc((size_t)n * 2 * COUT * 4);
    int*  bcnt  = (int*)alloc((size_t)2 * nb * 4);
    int*  bbase = (int*)alloc((size_t)2 * (nb + 1) * 4);
    int*  bcur  = (int*)alloc((size_t)2 * nb * 4);
    ushort* Wsw = (ushort*)alloc((size_t)2 * 16 * 8 * 64 * 8 * 2);

    const int rowBlocks = (n + 3) / 4;

    hipLaunchKernelGGL(wprep_kernel, dim3(64), dim3(256), 0, stream, Win, Wsw);

    hipMemsetAsync(bcnt, 0, (size_t)2 * nb * 4, stream);
    hipLaunchKernelGGL(bhist_kernel, dim3(256, 2), dim3(256), nb * 4, stream,
                       ei1, E1, ei2, E2, bcnt, nb);
    hipLaunchKernelGGL(bscan_kernel, dim3(1, 2), dim3(256), 0, stream,
                       bcnt, bbase, bcur, rowp1, rowp2, nb, n, E1, E2);
    hipLaunchKernelGGL(bscat_kernel, dim3(SCAT_BLOCKS, 2), dim3(256), 2 * nb * 4, stream,
                       ei1, ei1 + E1, ew1, E1, ei2, ei2 + E2, ew2, E2,
                       bcur, tcw1, tcw2, nb);
    hipLaunchKernelGGL(bsort_kernel, dim3(nb, 2), dim3(256), 0, stream,
                       bbase, tcw1, tcw2, rowp1, rowp2, cw1, cw2, nb, n);

    hipLaunchKernelGGL(gemm_mfma_kernel, dim3((n + 127) / 128, 2), dim3(256), 0, stream,
                       x, Wsw, bin, h1A, h2A, n);

    hipLaunchKernelGGL(zacc2_kernel, dim3(rowBlocks), dim3(256), 0, stream,
                       h1A, h2A, Wout, fW, z2, n);

    uint* cur1 = h1A; uint* nxt1 = h1B;
    uint* cur2 = h2A; uint* nxt2 = h2B;
    for (int k = 0; k < KHOPS; ++k) {
        const int storeH = (k < KHOPS - 1) ? 1 : 0;
        BrArgs A { rowp1, cw1, cur1, nxt1, Wout };
        BrArgs B { rowp2, cw2, cur2, nxt2, Wout + (size_t)HID * COUT };
        hipLaunchKernelGGL(spmm2_kernel, dim3(rowBlocks * 2), dim3(256), 0, stream,
                           A, B, fW, k, z2, storeH, n);
        uint* t1 = cur1; cur1 = nxt1; nxt1 = t1;
        uint* t2 = cur2; cur2 = nxt2; nxt2 = t2;
    }

    hipLaunchKernelGGL(logsm_kernel, dim3((n + 255) / 256), dim3(256), 0, stream,
                       z2, bout, zout, n);
}